// Round 9
// baseline (368.273 us; speedup 1.0000x reference)
//
#include <hip/hip_runtime.h>

// ---------------------------------------------------------------------------
// 2-layer GCN + link-prediction dot products.
// R22 = R21 with gemm1 register DEMAND cut below the allocator's target.
// R21 falsified "raise the budget": launch_bounds(256,4) left VGPR at 52 and
// the ~63MB scratch-spill writes intact (WRITE 69MB vs 6.4MB legit). The
// allocator targets ~52 VGPR regardless of permitted budget, so the fix is
// demand: buf[8]->buf[4] (16-col chunks, 16 iters). Live set = acc 16 +
// buf 16 + addr ~10 < 52. Wave-load still covers 16 full 64B lines per 1KB
// (same line traffic as 32-col chunks). LDS 20KB pitch-5-f4 (same 8-lane/
// 4-bank-slot class as R20's pitch-9, measured 0 conflicts).
//
// hs = (x@W1) * dinv
// gs = relu(dinv*(gather(hs)+hs)+b1) * dinv
// u  = dinv*(gather(gs)+gs);  y = u@M + w2b;  c = u.w2b
// logits[e] = y[a].u[b] + c[a] + bb     (M = W2 W2^T, w2b = W2 b2, bb = b2.b2)
// ---------------------------------------------------------------------------

#define NB_SHIFT 8
#define CAP   9728    // slots per 256-node bucket (mean 8192, +17 sigma)
#define CHUNK 8192    // edges per passA1 block

// gtail seed + (M, w2b, bb) precompute in one tiny launch
__global__ void seedprep_kernel(int* __restrict__ gtail, int nb1,
                                const float* __restrict__ W2, const float* __restrict__ b2,
                                float* __restrict__ mw) {
    int t = threadIdx.x;
    for (int i = t; i < nb1; i += 256) gtail[i] = i * CAP;
    int r = t >> 4, cc = t & 15;
    float s = 0.0f;
    for (int j = 0; j < 64; ++j) s += W2[r * 64 + j] * W2[cc * 64 + j];
    mw[t] = s;
    if (t < 16) {
        float w = 0.0f;
        for (int j = 0; j < 64; ++j) w += W2[t * 64 + j] * b2[j];
        mw[256 + t] = w;
    }
    if (t == 0) {
        float bbv = 0.0f;
        for (int j = 0; j < 64; ++j) bbv += b2[j] * b2[j];
        mw[272] = bbv;
    }
}

// hs[rb..rb+255][:] = x[rows] @ W1 (UNSCALED; dinv applied in fill2).
// Per 16-col chunk: stage 256x16 tile to LDS coalesced (wave-load = 16 rows
// x 64B full lines), prefetch next chunk into buf[4] during compute.
__global__ void __launch_bounds__(256)
gemm1_kernel(const float* __restrict__ x, const float* __restrict__ W1,
             float* __restrict__ hs, int n) {
    __shared__ float4 sx[256 * 5];          // pitch 5 f4 = 20KB
    int t = threadIdx.x;
    int rb = blockIdx.x << 8;               // 256 rows per block
    const float4* W14 = (const float4*)W1;  // uniform-indexed -> s_load
    float4 a0 = {0,0,0,0}, a1 = {0,0,0,0}, a2 = {0,0,0,0}, a3 = {0,0,0,0};
    float4 zero = {0,0,0,0};
    float4 buf[4];
    // prefetch chunk 0: flat f4 index = t + 256j -> (row flat>>2, col flat&3)
    #pragma unroll
    for (int j = 0; j < 4; ++j) {
        int flat = t + (j << 8);
        int r = flat >> 2, c = flat & 3;
        int gr = rb + r;
        buf[j] = (gr < n) ? ((const float4*)(x + (size_t)gr * 256))[c] : zero;
    }
    for (int ch = 0; ch < 16; ++ch) {
        #pragma unroll
        for (int j = 0; j < 4; ++j) {
            int flat = t + (j << 8);
            sx[(flat >> 2) * 5 + (flat & 3)] = buf[j];
        }
        __syncthreads();
        if (ch < 15) {
            #pragma unroll
            for (int j = 0; j < 4; ++j) {
                int flat = t + (j << 8);
                int r = flat >> 2, c = flat & 3;
                int gr = rb + r;
                buf[j] = (gr < n)
                    ? ((const float4*)(x + (size_t)gr * 256))[(ch + 1) * 4 + c] : zero;
            }
        }
        #pragma unroll
        for (int c = 0; c < 4; ++c) {
            float4 xv = sx[t * 5 + c];
            int k4 = ch * 4 + c;
            #pragma unroll
            for (int j = 0; j < 4; ++j) {
                float xk = (j == 0) ? xv.x : (j == 1) ? xv.y : (j == 2) ? xv.z : xv.w;
                int k = (k4 << 2) + j;
                float4 w0 = W14[k * 4 + 0];
                float4 w1 = W14[k * 4 + 1];
                float4 w2 = W14[k * 4 + 2];
                float4 w3 = W14[k * 4 + 3];
                a0.x += xk * w0.x; a0.y += xk * w0.y; a0.z += xk * w0.z; a0.w += xk * w0.w;
                a1.x += xk * w1.x; a1.y += xk * w1.y; a1.z += xk * w1.z; a1.w += xk * w1.w;
                a2.x += xk * w2.x; a2.y += xk * w2.y; a2.z += xk * w2.z; a2.w += xk * w2.w;
                a3.x += xk * w3.x; a3.y += xk * w3.y; a3.z += xk * w3.z; a3.w += xk * w3.w;
            }
        }
        __syncthreads();
    }
    int row = rb + t;
    if (row < n) {
        float4* o = (float4*)(hs + (size_t)row * 16);
        o[0] = a0; o[1] = a1; o[2] = a2; o[3] = a3;
    }
}

// one block per CHUNK of edges: LDS bucket-sort, then coalesced run writes
// into per-bucket global regions reserved via gtail. (R14-measured version.)
__global__ void __launch_bounds__(512)
passA1_kernel(const int* __restrict__ src, const int* __restrict__ dst, int E,
              int* __restrict__ gtail, unsigned* __restrict__ tmp, int nb1) {
    __shared__ int h[512];
    __shared__ int loff[512];
    __shared__ int cur[512];
    __shared__ int base[512];
    __shared__ unsigned srec[CHUNK];
    __shared__ unsigned short sbkt[CHUNK];
    int t = threadIdx.x;
    int c0 = blockIdx.x * CHUNK;
    int ce = min(CHUNK, E - c0);

    h[t] = 0;
    __syncthreads();
    // pass 1: bucket histogram (dst chunk is 32KB -> L1/L2-hot for pass 2)
    for (int i = t; i < ce; i += 512)
        atomicAdd(&h[dst[c0 + i] >> NB_SHIFT], 1);
    __syncthreads();
    // parallel inclusive scan over 512 entries
    int cnt = h[t];
    loff[t] = cnt;
    __syncthreads();
    for (int off = 1; off < 512; off <<= 1) {
        int v = loff[t];
        int a = (t >= off) ? loff[t - off] : 0;
        __syncthreads();
        loff[t] = v + a;
        __syncthreads();
    }
    int excl = loff[t] - cnt;
    // reserve per-bucket global regions
    if (t < nb1) base[t] = atomicAdd(&gtail[t], cnt);
    loff[t] = excl;
    cur[t]  = excl;
    __syncthreads();
    // pass 2: place records into LDS sorted by bucket
    for (int i = t; i < ce; i += 512) {
        int d = dst[c0 + i];
        int s = src[c0 + i];
        int b = d >> NB_SHIFT;
        int p = atomicAdd(&cur[b], 1);
        srec[p] = (unsigned)s | ((unsigned)(d & 255) << 20);
        sbkt[p] = (unsigned short)b;
    }
    __syncthreads();
    // pass 3: stream out — consecutive i mostly share a bucket (runs ~21 recs)
    for (int i = t; i < ce; i += 512) {
        int b = sbkt[i];
        tmp[base[b] + (i - loff[b])] = srec[i];
    }
}

// one block per coarse bucket: hist -> parallel scan -> rowptr/counts/dinv,
// fine-sort into LDS staging, coalesced eidx write, then scale this bucket's
// hs rows by dinv (completes the deferred gemm epilogue).
__global__ void __launch_bounds__(512)
fill2_kernel(const int* __restrict__ gtail, const unsigned* __restrict__ tmp,
             int* __restrict__ eidx, int* __restrict__ rowptr,
             int* __restrict__ counts, float* __restrict__ dinv,
             float* __restrict__ hs, int n) {
    __shared__ int hh[256];
    __shared__ int sc[256];
    __shared__ int cur[256];
    __shared__ float sdinv[256];
    __shared__ int sout[CAP];
    int b = blockIdx.x;
    int t = threadIdx.x;
    int beg = b * CAP;
    int cnt_total = gtail[b] - beg;

    if (t < 256) hh[t] = 0;
    __syncthreads();
    for (int i = t; i < cnt_total; i += 512)
        atomicAdd(&hh[tmp[beg + i] >> 20], 1);
    __syncthreads();
    if (t < 256) sc[t] = hh[t];
    __syncthreads();
    // parallel inclusive scan over 256 fine nodes
    for (int off = 1; off < 256; off <<= 1) {
        int v = 0, a = 0;
        if (t < 256) { v = sc[t]; a = (t >= off) ? sc[t - off] : 0; }
        __syncthreads();
        if (t < 256) sc[t] = v + a;
        __syncthreads();
    }
    if (t < 256) {
        int ex = sc[t] - hh[t];
        cur[t] = ex;
        float dv = rsqrtf((float)hh[t] + 1.0f);   // +1: self loop
        sdinv[t] = dv;
        int v = (b << NB_SHIFT) + t;
        if (v < n) {
            rowptr[v] = beg + ex;
            counts[v] = hh[t];
            dinv[v]   = dv;
        }
    }
    __syncthreads();
    // place into LDS staging (fine-sorted)
    for (int i = t; i < cnt_total; i += 512) {
        unsigned r = tmp[beg + i];
        int p = atomicAdd(&cur[r >> 20], 1);
        sout[p] = (int)(r & 0xFFFFF);
    }
    __syncthreads();
    // coalesced stream out
    for (int i = t; i < cnt_total; i += 512)
        eidx[beg + i] = sout[i];
    // deferred gemm epilogue: hs[row] *= dinv[row] for this bucket's rows
    int v0 = b << NB_SHIFT;
    int rows = min(256, n - v0);
    if (rows > 0) {
        float4* h4 = (float4*)(hs + (size_t)v0 * 16);
        int tot = rows * 4;
        for (int i = t; i < tot; i += 512) {
            float4 hv = h4[i];
            float dv = sdinv[i >> 2];
            hv.x *= dv; hv.y *= dv; hv.z *= dv; hv.w *= dv;
            h4[i] = hv;
        }
    }
}

// layer-1 aggregate: 8 lanes/node (2 per feature-quad), unroll-4 gathers.
__global__ void agg1_kernel(const int* __restrict__ rowptr, const int* __restrict__ counts,
                            const int* __restrict__ eidx, const float4* __restrict__ hs4,
                            const float* __restrict__ dinv, const float* __restrict__ b1,
                            float4* __restrict__ gs4, int n) {
    int t = blockIdx.x * blockDim.x + threadIdx.x;
    int v = t >> 3;
    if (v >= n) return;
    int q = t & 3, hh = (t >> 2) & 1;
    int start = rowptr[v], cnt = counts[v];
    float4 s = {0, 0, 0, 0};
    int i = hh;
    for (; i + 6 < cnt; i += 8) {
        int s0 = eidx[start + i];
        int s1 = eidx[start + i + 2];
        int s2 = eidx[start + i + 4];
        int s3 = eidx[start + i + 6];
        float4 h0 = hs4[(size_t)s0 * 4 + q];
        float4 h1 = hs4[(size_t)s1 * 4 + q];
        float4 h2 = hs4[(size_t)s2 * 4 + q];
        float4 h3 = hs4[(size_t)s3 * 4 + q];
        s.x += h0.x + h1.x + h2.x + h3.x;
        s.y += h0.y + h1.y + h2.y + h3.y;
        s.z += h0.z + h1.z + h2.z + h3.z;
        s.w += h0.w + h1.w + h2.w + h3.w;
    }
    for (; i < cnt; i += 2) {
        float4 h0 = hs4[(size_t)eidx[start + i] * 4 + q];
        s.x += h0.x; s.y += h0.y; s.z += h0.z; s.w += h0.w;
    }
    // merge the two edge-halves (lanes differing in bit 2)
    s.x += __shfl_xor(s.x, 4);
    s.y += __shfl_xor(s.y, 4);
    s.z += __shfl_xor(s.z, 4);
    s.w += __shfl_xor(s.w, 4);
    if (hh == 0) {
        float di = dinv[v];
        float4 h = hs4[(size_t)v * 4 + q];
        float4 b = ((const float4*)b1)[q];
        float4 z;
        z.x = fmaxf(di * (s.x + h.x) + b.x, 0.0f) * di;
        z.y = fmaxf(di * (s.y + h.y) + b.y, 0.0f) * di;
        z.z = fmaxf(di * (s.z + h.z) + b.z, 0.0f) * di;
        z.w = fmaxf(di * (s.w + h.w) + b.w, 0.0f) * di;
        gs4[(size_t)v * 4 + q] = z;
    }
}

// layer-2 aggregate + factorized epilogue: u = dinv*(gather(gs)+gs);
// y = u@M + w2b; c = u.w2b.  256 threads = 32 nodes x 8 lanes.
__global__ void agg2y_kernel(const int* __restrict__ rowptr, const int* __restrict__ counts,
                             const int* __restrict__ eidx, const float4* __restrict__ gs4,
                             const float* __restrict__ dinv, const float* __restrict__ mw,
                             float4* __restrict__ u4, float* __restrict__ y,
                             float* __restrict__ c, int n) {
    __shared__ float su[32 * 16];   // u for this block's 32 nodes
    __shared__ float sM[256];
    __shared__ float sw[16];
    int t = threadIdx.x;
    sM[t] = mw[t];
    if (t < 16) sw[t] = mw[256 + t];

    int j = t >> 3, q = t & 3, hh = (t >> 2) & 1;
    int v = blockIdx.x * 32 + j;
    if (v < n) {
        int start = rowptr[v], cnt = counts[v];
        float4 s = {0, 0, 0, 0};
        int i = hh;
        for (; i + 6 < cnt; i += 8) {
            int s0 = eidx[start + i];
            int s1 = eidx[start + i + 2];
            int s2 = eidx[start + i + 4];
            int s3 = eidx[start + i + 6];
            float4 g0 = gs4[(size_t)s0 * 4 + q];
            float4 g1 = gs4[(size_t)s1 * 4 + q];
            float4 g2 = gs4[(size_t)s2 * 4 + q];
            float4 g3 = gs4[(size_t)s3 * 4 + q];
            s.x += g0.x + g1.x + g2.x + g3.x;
            s.y += g0.y + g1.y + g2.y + g3.y;
            s.z += g0.z + g1.z + g2.z + g3.z;
            s.w += g0.w + g1.w + g2.w + g3.w;
        }
        for (; i < cnt; i += 2) {
            float4 g0 = gs4[(size_t)eidx[start + i] * 4 + q];
            s.x += g0.x; s.y += g0.y; s.z += g0.z; s.w += g0.w;
        }
        s.x += __shfl_xor(s.x, 4);
        s.y += __shfl_xor(s.y, 4);
        s.z += __shfl_xor(s.z, 4);
        s.w += __shfl_xor(s.w, 4);
        if (hh == 0) {
            float di = dinv[v];
            float4 g = gs4[(size_t)v * 4 + q];
            float4 uu;
            uu.x = di * (s.x + g.x);
            uu.y = di * (s.y + g.y);
            uu.z = di * (s.z + g.z);
            uu.w = di * (s.w + g.w);
            float* up = &su[j * 16 + q * 4];
            up[0] = uu.x; up[1] = uu.y; up[2] = uu.z; up[3] = uu.w;
            u4[(size_t)v * 4 + q] = uu;
        }
    }
    __syncthreads();
    if (v < n) {
        int l8 = t & 7;
        const float* uu = &su[j * 16];
        int c0 = l8 * 2;
        float y0 = sw[c0], y1 = sw[c0 + 1];
        #pragma unroll
        for (int k = 0; k < 16; ++k) {
            float uk = uu[k];
            y0 += uk * sM[k * 16 + c0];
            y1 += uk * sM[k * 16 + c0 + 1];
        }
        float2* yp = (float2*)(y + (size_t)v * 16 + c0);
        *yp = make_float2(y0, y1);
        if (l8 == 0) {
            float cv = 0.0f;
            #pragma unroll
            for (int k = 0; k < 16; ++k) cv += uu[k] * sw[k];
            c[v] = cv;
        }
    }
}

// 16 lanes per pair: one pos edge + one neg edge.
// logit = y[a].u[b] + c[a] + bb
__global__ void edge_dot_kernel(const int* __restrict__ pa, const int* __restrict__ pb,
                                const int* __restrict__ na, const int* __restrict__ nb_,
                                int ET, const float* __restrict__ u, const float* __restrict__ y,
                                const float* __restrict__ c, const float* __restrict__ mw,
                                float* __restrict__ out) {
    int t = blockIdx.x * blockDim.x + threadIdx.x;
    int p = t >> 4, l = t & 15;
    if (p >= ET) return;
    int a0 = pa[p], b0 = pb[p];
    int a1 = na[p], b1 = nb_[p];
    float ya0 = y[(size_t)a0 * 16 + l];
    float ub0 = u[(size_t)b0 * 16 + l];
    float ya1 = y[(size_t)a1 * 16 + l];
    float ub1 = u[(size_t)b1 * 16 + l];
    float p0 = ya0 * ub0;
    float p1 = ya1 * ub1;
    p0 += __shfl_xor(p0, 1);  p1 += __shfl_xor(p1, 1);
    p0 += __shfl_xor(p0, 2);  p1 += __shfl_xor(p1, 2);
    p0 += __shfl_xor(p0, 4);  p1 += __shfl_xor(p1, 4);
    p0 += __shfl_xor(p0, 8);  p1 += __shfl_xor(p1, 8);
    if (l == 0) {
        float bb = mw[272];
        out[p]      = p0 + c[a0] + bb;
        out[ET + p] = p1 + c[a1] + bb;
    }
}

extern "C" void kernel_launch(void* const* d_in, const int* in_sizes, int n_in,
                              void* d_out, int out_size, void* d_ws, size_t ws_size,
                              hipStream_t stream) {
    const float* x    = (const float*)d_in[0];
    const int*   tei  = (const int*)d_in[1];
    const int*   tpos = (const int*)d_in[2];
    const int*   tneg = (const int*)d_in[3];
    const float* W1   = (const float*)d_in[4];
    const float* b1   = (const float*)d_in[5];
    const float* W2   = (const float*)d_in[6];
    const float* b2   = (const float*)d_in[7];
    float* out = (float*)d_out;

    int n   = in_sizes[0] / 256;         // 100000 nodes
    int E   = in_sizes[1] / 2;           // 3.2M train edges
    int ET  = in_sizes[2] / 2;           // 500K test edges each
    int nb1 = (n + 255) >> NB_SHIFT;     // 391 coarse buckets (256 nodes each)

    // workspace layout (no aliasing)
    char* w = (char*)d_ws;
    int*   gtail  = (int*)w;        w += 512 * 4;
    float* mw     = (float*)w;      w += 512 * 4;
    int*   rowptr = (int*)w;        w += (size_t)n * 4;
    int*   counts = (int*)w;        w += (size_t)n * 4;
    float* dinv   = (float*)w;      w += (size_t)n * 4;
    float* hs     = (float*)w;      w += (size_t)16 * n * 4;
    float* gs     = (float*)w;      w += (size_t)16 * n * 4;
    float* u      = (float*)w;      w += (size_t)16 * n * 4;
    float* y      = (float*)w;      w += (size_t)16 * n * 4;
    float* c      = (float*)w;      w += (size_t)n * 4;
    int*   eidx   = (int*)w;        w += (size_t)nb1 * CAP * 4;
    unsigned* tmp = (unsigned*)w;   w += (size_t)nb1 * CAP * 4;

    const int* src = tei;
    const int* dst = tei + E;

    seedprep_kernel<<<1, 256, 0, stream>>>(gtail, nb1, W2, b2, mw);
    gemm1_kernel<<<(n + 255) / 256, 256, 0, stream>>>(x, W1, hs, n);
    passA1_kernel<<<(E + CHUNK - 1) / CHUNK, 512, 0, stream>>>(src, dst, E, gtail, tmp, nb1);
    fill2_kernel<<<nb1, 512, 0, stream>>>(gtail, tmp, eidx, rowptr, counts, dinv, hs, n);

    agg1_kernel<<<(8 * n + 255) / 256, 256, 0, stream>>>(rowptr, counts, eidx,
                                                         (const float4*)hs, dinv, b1,
                                                         (float4*)gs, n);
    agg2y_kernel<<<(n + 31) / 32, 256, 0, stream>>>(rowptr, counts, eidx,
                                                    (const float4*)gs, dinv, mw,
                                                    (float4*)u, y, c, n);
    edge_dot_kernel<<<(16 * ET + 255) / 256, 256, 0, stream>>>(tpos, tpos + ET, tneg, tneg + ET,
                                                               ET, u, y, c, mw, out);
}

// Round 10
// 338.781 us; speedup vs baseline: 1.0871x; 1.0871x over previous
//
#include <hip/hip_runtime.h>
#include <hip/hip_fp16.h>

// ---------------------------------------------------------------------------
// 2-layer GCN + link-prediction dot products.
// R23: (a) revert gemm1 to the R14-measured 64-thread form (~57us inferred;
// the R20-R22 "coalesced" redesign was itself the regression: 74-76us
// invariant across VGPR 52/52/28, LDS 36/36/20KB -- allocator spills
// regardless, fallback triggered). (b) ONE new lever: hs stored as fp16.
// agg1's gather is 3.2M x 64B = 205MB logical from a 6.4MB table > 4MB
// per-XCD L2 -> L3-served. fp16 halves gather bytes AND makes the table
// 3.2MB = per-XCD-L2-resident. gs stays fp32 (risk-staged; absmax is the
// pre-committed read: pass -> extend to gs next round, fail -> revert fp16).
//
// hs = (x@W1) * dinv   [fp16 storage]
// gs = relu(dinv*(gather(hs)+hs)+b1) * dinv   [fp32]
// u  = dinv*(gather(gs)+gs);  y = u@M + w2b;  c = u.w2b
// logits[e] = y[a].u[b] + c[a] + bb     (M = W2 W2^T, w2b = W2 b2, bb = b2.b2)
// ---------------------------------------------------------------------------

#define NB_SHIFT 8
#define CAP   9728    // slots per 256-node bucket (mean 8192, +17 sigma)
#define CHUNK 8192    // edges per passA1 block

// gtail seed + (M, w2b, bb) precompute in one tiny launch
__global__ void seedprep_kernel(int* __restrict__ gtail, int nb1,
                                const float* __restrict__ W2, const float* __restrict__ b2,
                                float* __restrict__ mw) {
    int t = threadIdx.x;
    for (int i = t; i < nb1; i += 256) gtail[i] = i * CAP;
    int r = t >> 4, cc = t & 15;
    float s = 0.0f;
    for (int j = 0; j < 64; ++j) s += W2[r * 64 + j] * W2[cc * 64 + j];
    mw[t] = s;
    if (t < 16) {
        float w = 0.0f;
        for (int j = 0; j < 64; ++j) w += W2[t * 64 + j] * b2[j];
        mw[256 + t] = w;
    }
    if (t == 0) {
        float bbv = 0.0f;
        for (int j = 0; j < 64; ++j) bbv += b2[j] * b2[j];
        mw[272] = bbv;
    }
}

// one block per CHUNK of edges: LDS bucket-sort, then coalesced run writes
// into per-bucket global regions reserved via gtail. (R14-measured version.)
__global__ void __launch_bounds__(512)
passA1_kernel(const int* __restrict__ src, const int* __restrict__ dst, int E,
              int* __restrict__ gtail, unsigned* __restrict__ tmp, int nb1) {
    __shared__ int h[512];
    __shared__ int loff[512];
    __shared__ int cur[512];
    __shared__ int base[512];
    __shared__ unsigned srec[CHUNK];
    __shared__ unsigned short sbkt[CHUNK];
    int t = threadIdx.x;
    int c0 = blockIdx.x * CHUNK;
    int ce = min(CHUNK, E - c0);

    h[t] = 0;
    __syncthreads();
    // pass 1: bucket histogram (dst chunk is 32KB -> L1/L2-hot for pass 2)
    for (int i = t; i < ce; i += 512)
        atomicAdd(&h[dst[c0 + i] >> NB_SHIFT], 1);
    __syncthreads();
    // parallel inclusive scan over 512 entries
    int cnt = h[t];
    loff[t] = cnt;
    __syncthreads();
    for (int off = 1; off < 512; off <<= 1) {
        int v = loff[t];
        int a = (t >= off) ? loff[t - off] : 0;
        __syncthreads();
        loff[t] = v + a;
        __syncthreads();
    }
    int excl = loff[t] - cnt;
    // reserve per-bucket global regions
    if (t < nb1) base[t] = atomicAdd(&gtail[t], cnt);
    loff[t] = excl;
    cur[t]  = excl;
    __syncthreads();
    // pass 2: place records into LDS sorted by bucket
    for (int i = t; i < ce; i += 512) {
        int d = dst[c0 + i];
        int s = src[c0 + i];
        int b = d >> NB_SHIFT;
        int p = atomicAdd(&cur[b], 1);
        srec[p] = (unsigned)s | ((unsigned)(d & 255) << 20);
        sbkt[p] = (unsigned short)b;
    }
    __syncthreads();
    // pass 3: stream out — consecutive i mostly share a bucket (runs ~21 recs)
    for (int i = t; i < ce; i += 512) {
        int b = sbkt[i];
        tmp[base[b] + (i - loff[b])] = srec[i];
    }
}

// one block per coarse bucket: hist -> parallel scan -> rowptr/counts/dinv,
// fine-sort into LDS staging, coalesced eidx write. (R14-measured version;
// no hs epilogue -- gemm1 runs after this and applies dinv inline.)
__global__ void __launch_bounds__(512)
fill2_kernel(const int* __restrict__ gtail, const unsigned* __restrict__ tmp,
             int* __restrict__ eidx, int* __restrict__ rowptr,
             int* __restrict__ counts, float* __restrict__ dinv, int n) {
    __shared__ int hh[256];
    __shared__ int sc[256];
    __shared__ int cur[256];
    __shared__ int sout[CAP];
    int b = blockIdx.x;
    int t = threadIdx.x;
    int beg = b * CAP;
    int cnt_total = gtail[b] - beg;

    if (t < 256) hh[t] = 0;
    __syncthreads();
    for (int i = t; i < cnt_total; i += 512)
        atomicAdd(&hh[tmp[beg + i] >> 20], 1);
    __syncthreads();
    if (t < 256) sc[t] = hh[t];
    __syncthreads();
    // parallel inclusive scan over 256 fine nodes
    for (int off = 1; off < 256; off <<= 1) {
        int v = 0, a = 0;
        if (t < 256) { v = sc[t]; a = (t >= off) ? sc[t - off] : 0; }
        __syncthreads();
        if (t < 256) sc[t] = v + a;
        __syncthreads();
    }
    if (t < 256) {
        int ex = sc[t] - hh[t];
        cur[t] = ex;
        int v = (b << NB_SHIFT) + t;
        if (v < n) {
            rowptr[v] = beg + ex;
            counts[v] = hh[t];
            dinv[v]   = rsqrtf((float)hh[t] + 1.0f);   // +1: self loop
        }
    }
    __syncthreads();
    // place into LDS staging (fine-sorted)
    for (int i = t; i < cnt_total; i += 512) {
        unsigned r = tmp[beg + i];
        int p = atomicAdd(&cur[r >> 20], 1);
        sout[p] = (int)(r & 0xFFFFF);
    }
    __syncthreads();
    // coalesced stream out
    for (int i = t; i < cnt_total; i += 512)
        eidx[beg + i] = sout[i];
}

// hs[row][:] = (x[row][:] @ W1) * dinv[row], stored fp16.  1 row/thread,
// 64-thread single-wave blocks (R14-measured structure); W1 via wave-uniform
// s_load; x prefetched 8-deep into registers for memory-level parallelism.
__global__ void __launch_bounds__(64)
gemm1_kernel(const float* __restrict__ x, const float* __restrict__ W1,
             const float* __restrict__ dinv, __half* __restrict__ hs, int n) {
    int row = blockIdx.x * 64 + threadIdx.x;
    if (row >= n) return;
    const float4* x4 = (const float4*)(x + (size_t)row * 256);
    const float4* W14 = (const float4*)W1;   // uniform-indexed -> s_load
    float4 a0 = {0,0,0,0}, a1 = {0,0,0,0}, a2 = {0,0,0,0}, a3 = {0,0,0,0};
    float4 buf[8];
    #pragma unroll
    for (int j = 0; j < 8; ++j) buf[j] = x4[j];
    for (int k8 = 0; k8 < 8; ++k8) {
        float4 cur[8];
        #pragma unroll
        for (int j = 0; j < 8; ++j) cur[j] = buf[j];
        if (k8 < 7) {
            #pragma unroll
            for (int j = 0; j < 8; ++j) buf[j] = x4[(k8 + 1) * 8 + j];
        }
        #pragma unroll
        for (int jj = 0; jj < 8; ++jj) {
            float4 xv = cur[jj];
            int k4 = k8 * 8 + jj;
            #pragma unroll
            for (int j = 0; j < 4; ++j) {
                float xk = (j == 0) ? xv.x : (j == 1) ? xv.y : (j == 2) ? xv.z : xv.w;
                int k = (k4 << 2) + j;
                float4 w0 = W14[k * 4 + 0];
                float4 w1 = W14[k * 4 + 1];
                float4 w2 = W14[k * 4 + 2];
                float4 w3 = W14[k * 4 + 3];
                a0.x += xk * w0.x; a0.y += xk * w0.y; a0.z += xk * w0.z; a0.w += xk * w0.w;
                a1.x += xk * w1.x; a1.y += xk * w1.y; a1.z += xk * w1.z; a1.w += xk * w1.w;
                a2.x += xk * w2.x; a2.y += xk * w2.y; a2.z += xk * w2.z; a2.w += xk * w2.w;
                a3.x += xk * w3.x; a3.y += xk * w3.y; a3.z += xk * w3.z; a3.w += xk * w3.w;
            }
        }
    }
    float di = dinv[row];
    union { __half2 h2[8]; uint4 u4[2]; } pk;
    pk.h2[0] = __floats2half2_rn(a0.x * di, a0.y * di);
    pk.h2[1] = __floats2half2_rn(a0.z * di, a0.w * di);
    pk.h2[2] = __floats2half2_rn(a1.x * di, a1.y * di);
    pk.h2[3] = __floats2half2_rn(a1.z * di, a1.w * di);
    pk.h2[4] = __floats2half2_rn(a2.x * di, a2.y * di);
    pk.h2[5] = __floats2half2_rn(a2.z * di, a2.w * di);
    pk.h2[6] = __floats2half2_rn(a3.x * di, a3.y * di);
    pk.h2[7] = __floats2half2_rn(a3.z * di, a3.w * di);
    uint4* o = (uint4*)(hs + (size_t)row * 16);
    o[0] = pk.u4[0];
    o[1] = pk.u4[1];
}

// layer-1 aggregate: 8 lanes/node (2 per feature-quad), unroll-4 gathers.
// hs is fp16: each gather is 8B (uint2 = 4 halfs), table 3.2MB (L2-resident).
__global__ void agg1_kernel(const int* __restrict__ rowptr, const int* __restrict__ counts,
                            const int* __restrict__ eidx, const __half* __restrict__ hsh,
                            const float* __restrict__ dinv, const float* __restrict__ b1,
                            float4* __restrict__ gs4, int n) {
    const uint2* h2p = (const uint2*)hsh;    // 4 uint2 per 16-half row
    int t = blockIdx.x * blockDim.x + threadIdx.x;
    int v = t >> 3;
    if (v >= n) return;
    int q = t & 3, hh = (t >> 2) & 1;
    int start = rowptr[v], cnt = counts[v];
    float4 s = {0, 0, 0, 0};
    int i = hh;
    for (; i + 6 < cnt; i += 8) {
        int s0 = eidx[start + i];
        int s1 = eidx[start + i + 2];
        int s2 = eidx[start + i + 4];
        int s3 = eidx[start + i + 6];
        uint2 r0 = h2p[(size_t)s0 * 4 + q];
        uint2 r1 = h2p[(size_t)s1 * 4 + q];
        uint2 r2 = h2p[(size_t)s2 * 4 + q];
        uint2 r3 = h2p[(size_t)s3 * 4 + q];
        float2 f0a = __half22float2(*(__half2*)&r0.x), f0b = __half22float2(*(__half2*)&r0.y);
        float2 f1a = __half22float2(*(__half2*)&r1.x), f1b = __half22float2(*(__half2*)&r1.y);
        float2 f2a = __half22float2(*(__half2*)&r2.x), f2b = __half22float2(*(__half2*)&r2.y);
        float2 f3a = __half22float2(*(__half2*)&r3.x), f3b = __half22float2(*(__half2*)&r3.y);
        s.x += f0a.x + f1a.x + f2a.x + f3a.x;
        s.y += f0a.y + f1a.y + f2a.y + f3a.y;
        s.z += f0b.x + f1b.x + f2b.x + f3b.x;
        s.w += f0b.y + f1b.y + f2b.y + f3b.y;
    }
    for (; i < cnt; i += 2) {
        uint2 r0 = h2p[(size_t)eidx[start + i] * 4 + q];
        float2 fa = __half22float2(*(__half2*)&r0.x), fb = __half22float2(*(__half2*)&r0.y);
        s.x += fa.x; s.y += fa.y; s.z += fb.x; s.w += fb.y;
    }
    // merge the two edge-halves (lanes differing in bit 2)
    s.x += __shfl_xor(s.x, 4);
    s.y += __shfl_xor(s.y, 4);
    s.z += __shfl_xor(s.z, 4);
    s.w += __shfl_xor(s.w, 4);
    if (hh == 0) {
        float di = dinv[v];
        uint2 rv = h2p[(size_t)v * 4 + q];
        float2 ha = __half22float2(*(__half2*)&rv.x), hb = __half22float2(*(__half2*)&rv.y);
        float4 b = ((const float4*)b1)[q];
        float4 z;
        z.x = fmaxf(di * (s.x + ha.x) + b.x, 0.0f) * di;
        z.y = fmaxf(di * (s.y + ha.y) + b.y, 0.0f) * di;
        z.z = fmaxf(di * (s.z + hb.x) + b.z, 0.0f) * di;
        z.w = fmaxf(di * (s.w + hb.y) + b.w, 0.0f) * di;
        gs4[(size_t)v * 4 + q] = z;
    }
}

// layer-2 aggregate + factorized epilogue: u = dinv*(gather(gs)+gs);
// y = u@M + w2b; c = u.w2b.  256 threads = 32 nodes x 8 lanes.
__global__ void agg2y_kernel(const int* __restrict__ rowptr, const int* __restrict__ counts,
                             const int* __restrict__ eidx, const float4* __restrict__ gs4,
                             const float* __restrict__ dinv, const float* __restrict__ mw,
                             float4* __restrict__ u4, float* __restrict__ y,
                             float* __restrict__ c, int n) {
    __shared__ float su[32 * 16];   // u for this block's 32 nodes
    __shared__ float sM[256];
    __shared__ float sw[16];
    int t = threadIdx.x;
    sM[t] = mw[t];
    if (t < 16) sw[t] = mw[256 + t];

    int j = t >> 3, q = t & 3, hh = (t >> 2) & 1;
    int v = blockIdx.x * 32 + j;
    if (v < n) {
        int start = rowptr[v], cnt = counts[v];
        float4 s = {0, 0, 0, 0};
        int i = hh;
        for (; i + 6 < cnt; i += 8) {
            int s0 = eidx[start + i];
            int s1 = eidx[start + i + 2];
            int s2 = eidx[start + i + 4];
            int s3 = eidx[start + i + 6];
            float4 g0 = gs4[(size_t)s0 * 4 + q];
            float4 g1 = gs4[(size_t)s1 * 4 + q];
            float4 g2 = gs4[(size_t)s2 * 4 + q];
            float4 g3 = gs4[(size_t)s3 * 4 + q];
            s.x += g0.x + g1.x + g2.x + g3.x;
            s.y += g0.y + g1.y + g2.y + g3.y;
            s.z += g0.z + g1.z + g2.z + g3.z;
            s.w += g0.w + g1.w + g2.w + g3.w;
        }
        for (; i < cnt; i += 2) {
            float4 g0 = gs4[(size_t)eidx[start + i] * 4 + q];
            s.x += g0.x; s.y += g0.y; s.z += g0.z; s.w += g0.w;
        }
        s.x += __shfl_xor(s.x, 4);
        s.y += __shfl_xor(s.y, 4);
        s.z += __shfl_xor(s.z, 4);
        s.w += __shfl_xor(s.w, 4);
        if (hh == 0) {
            float di = dinv[v];
            float4 g = gs4[(size_t)v * 4 + q];
            float4 uu;
            uu.x = di * (s.x + g.x);
            uu.y = di * (s.y + g.y);
            uu.z = di * (s.z + g.z);
            uu.w = di * (s.w + g.w);
            float* up = &su[j * 16 + q * 4];
            up[0] = uu.x; up[1] = uu.y; up[2] = uu.z; up[3] = uu.w;
            u4[(size_t)v * 4 + q] = uu;
        }
    }
    __syncthreads();
    if (v < n) {
        int l8 = t & 7;
        const float* uu = &su[j * 16];
        int c0 = l8 * 2;
        float y0 = sw[c0], y1 = sw[c0 + 1];
        #pragma unroll
        for (int k = 0; k < 16; ++k) {
            float uk = uu[k];
            y0 += uk * sM[k * 16 + c0];
            y1 += uk * sM[k * 16 + c0 + 1];
        }
        float2* yp = (float2*)(y + (size_t)v * 16 + c0);
        *yp = make_float2(y0, y1);
        if (l8 == 0) {
            float cv = 0.0f;
            #pragma unroll
            for (int k = 0; k < 16; ++k) cv += uu[k] * sw[k];
            c[v] = cv;
        }
    }
}

// 16 lanes per pair: one pos edge + one neg edge.
// logit = y[a].u[b] + c[a] + bb
__global__ void edge_dot_kernel(const int* __restrict__ pa, const int* __restrict__ pb,
                                const int* __restrict__ na, const int* __restrict__ nb_,
                                int ET, const float* __restrict__ u, const float* __restrict__ y,
                                const float* __restrict__ c, const float* __restrict__ mw,
                                float* __restrict__ out) {
    int t = blockIdx.x * blockDim.x + threadIdx.x;
    int p = t >> 4, l = t & 15;
    if (p >= ET) return;
    int a0 = pa[p], b0 = pb[p];
    int a1 = na[p], b1 = nb_[p];
    float ya0 = y[(size_t)a0 * 16 + l];
    float ub0 = u[(size_t)b0 * 16 + l];
    float ya1 = y[(size_t)a1 * 16 + l];
    float ub1 = u[(size_t)b1 * 16 + l];
    float p0 = ya0 * ub0;
    float p1 = ya1 * ub1;
    p0 += __shfl_xor(p0, 1);  p1 += __shfl_xor(p1, 1);
    p0 += __shfl_xor(p0, 2);  p1 += __shfl_xor(p1, 2);
    p0 += __shfl_xor(p0, 4);  p1 += __shfl_xor(p1, 4);
    p0 += __shfl_xor(p0, 8);  p1 += __shfl_xor(p1, 8);
    if (l == 0) {
        float bb = mw[272];
        out[p]      = p0 + c[a0] + bb;
        out[ET + p] = p1 + c[a1] + bb;
    }
}

extern "C" void kernel_launch(void* const* d_in, const int* in_sizes, int n_in,
                              void* d_out, int out_size, void* d_ws, size_t ws_size,
                              hipStream_t stream) {
    const float* x    = (const float*)d_in[0];
    const int*   tei  = (const int*)d_in[1];
    const int*   tpos = (const int*)d_in[2];
    const int*   tneg = (const int*)d_in[3];
    const float* W1   = (const float*)d_in[4];
    const float* b1   = (const float*)d_in[5];
    const float* W2   = (const float*)d_in[6];
    const float* b2   = (const float*)d_in[7];
    float* out = (float*)d_out;

    int n   = in_sizes[0] / 256;         // 100000 nodes
    int E   = in_sizes[1] / 2;           // 3.2M train edges
    int ET  = in_sizes[2] / 2;           // 500K test edges each
    int nb1 = (n + 255) >> NB_SHIFT;     // 391 coarse buckets (256 nodes each)

    // workspace layout (no aliasing)
    char* w = (char*)d_ws;
    int*   gtail  = (int*)w;        w += 512 * 4;
    float* mw     = (float*)w;      w += 512 * 4;
    int*   rowptr = (int*)w;        w += (size_t)n * 4;
    int*   counts = (int*)w;        w += (size_t)n * 4;
    float* dinv   = (float*)w;      w += (size_t)n * 4;
    __half* hs    = (__half*)w;     w += (size_t)16 * n * 2;   // fp16 table
    float* gs     = (float*)w;      w += (size_t)16 * n * 4;
    float* u      = (float*)w;      w += (size_t)16 * n * 4;
    float* y      = (float*)w;      w += (size_t)16 * n * 4;
    float* c      = (float*)w;      w += (size_t)n * 4;
    int*   eidx   = (int*)w;        w += (size_t)nb1 * CAP * 4;
    unsigned* tmp = (unsigned*)w;   w += (size_t)nb1 * CAP * 4;

    const int* src = tei;
    const int* dst = tei + E;

    seedprep_kernel<<<1, 256, 0, stream>>>(gtail, nb1, W2, b2, mw);
    passA1_kernel<<<(E + CHUNK - 1) / CHUNK, 512, 0, stream>>>(src, dst, E, gtail, tmp, nb1);
    fill2_kernel<<<nb1, 512, 0, stream>>>(gtail, tmp, eidx, rowptr, counts, dinv, n);

    gemm1_kernel<<<(n + 63) / 64, 64, 0, stream>>>(x, W1, dinv, hs, n);
    agg1_kernel<<<(8 * n + 255) / 256, 256, 0, stream>>>(rowptr, counts, eidx,
                                                         hs, dinv, b1,
                                                         (float4*)gs, n);
    agg2y_kernel<<<(n + 31) / 32, 256, 0, stream>>>(rowptr, counts, eidx,
                                                    (const float4*)gs, dinv, mw,
                                                    (float4*)u, y, c, n);
    edge_dot_kernel<<<(16 * ET + 255) / 256, 256, 0, stream>>>(tpos, tpos + ET, tneg, tneg + ET,
                                                               ET, u, y, c, mw, out);
}

// Round 11
// 325.330 us; speedup vs baseline: 1.1320x; 1.0413x over previous
//
#include <hip/hip_runtime.h>
#include <hip/hip_fp16.h>

// ---------------------------------------------------------------------------
// 2-layer GCN + link-prediction dot products.
// R24 = R23 + gather-transaction halving in BOTH agg kernels.
// R23 post-mortem: fp16 hs gained only ~11us (predicted 35) -> agg gathers
// are transaction-bound, not byte-bound (4 lanes x 8B per 32B row = 12.8M
// random transactions; halving bytes left transactions unchanged).
// Fix: (a) lane layout (f = 16B half, e = edge mod 4): each lane loads a
// full uint4 (8 halfs) -> 2 transactions/edge, unroll-4, merge via
// shfl_xor(2)+shfl_xor(4); (b) gs ALSO fp16 (hs proved absmax-free) ->
// agg2y table 3.2MB = per-XCD-L2-resident + same 2-transaction layout.
// u, y stay fp32 (edge_dot untouched).
//
// hs = (x@W1) * dinv        [fp16 storage]
// gs = relu(dinv*(gather(hs)+hs)+b1) * dinv   [fp16 storage]
// u  = dinv*(gather(gs)+gs);  y = u@M + w2b;  c = u.w2b   [fp32]
// logits[e] = y[a].u[b] + c[a] + bb     (M = W2 W2^T, w2b = W2 b2, bb = b2.b2)
// ---------------------------------------------------------------------------

#define NB_SHIFT 8
#define CAP   9728    // slots per 256-node bucket (mean 8192, +17 sigma)
#define CHUNK 8192    // edges per passA1 block

__device__ __forceinline__ void acc8(float* s, uint4 r) {
    float2 f0 = __half22float2(*(__half2*)&r.x);
    float2 f1 = __half22float2(*(__half2*)&r.y);
    float2 f2 = __half22float2(*(__half2*)&r.z);
    float2 f3 = __half22float2(*(__half2*)&r.w);
    s[0] += f0.x; s[1] += f0.y; s[2] += f1.x; s[3] += f1.y;
    s[4] += f2.x; s[5] += f2.y; s[6] += f3.x; s[7] += f3.y;
}

// gtail seed + (M, w2b, bb) precompute in one tiny launch
__global__ void seedprep_kernel(int* __restrict__ gtail, int nb1,
                                const float* __restrict__ W2, const float* __restrict__ b2,
                                float* __restrict__ mw) {
    int t = threadIdx.x;
    for (int i = t; i < nb1; i += 256) gtail[i] = i * CAP;
    int r = t >> 4, cc = t & 15;
    float s = 0.0f;
    for (int j = 0; j < 64; ++j) s += W2[r * 64 + j] * W2[cc * 64 + j];
    mw[t] = s;
    if (t < 16) {
        float w = 0.0f;
        for (int j = 0; j < 64; ++j) w += W2[t * 64 + j] * b2[j];
        mw[256 + t] = w;
    }
    if (t == 0) {
        float bbv = 0.0f;
        for (int j = 0; j < 64; ++j) bbv += b2[j] * b2[j];
        mw[272] = bbv;
    }
}

// one block per CHUNK of edges: LDS bucket-sort, then coalesced run writes
// into per-bucket global regions reserved via gtail. (R14-measured version.)
__global__ void __launch_bounds__(512)
passA1_kernel(const int* __restrict__ src, const int* __restrict__ dst, int E,
              int* __restrict__ gtail, unsigned* __restrict__ tmp, int nb1) {
    __shared__ int h[512];
    __shared__ int loff[512];
    __shared__ int cur[512];
    __shared__ int base[512];
    __shared__ unsigned srec[CHUNK];
    __shared__ unsigned short sbkt[CHUNK];
    int t = threadIdx.x;
    int c0 = blockIdx.x * CHUNK;
    int ce = min(CHUNK, E - c0);

    h[t] = 0;
    __syncthreads();
    for (int i = t; i < ce; i += 512)
        atomicAdd(&h[dst[c0 + i] >> NB_SHIFT], 1);
    __syncthreads();
    int cnt = h[t];
    loff[t] = cnt;
    __syncthreads();
    for (int off = 1; off < 512; off <<= 1) {
        int v = loff[t];
        int a = (t >= off) ? loff[t - off] : 0;
        __syncthreads();
        loff[t] = v + a;
        __syncthreads();
    }
    int excl = loff[t] - cnt;
    if (t < nb1) base[t] = atomicAdd(&gtail[t], cnt);
    loff[t] = excl;
    cur[t]  = excl;
    __syncthreads();
    for (int i = t; i < ce; i += 512) {
        int d = dst[c0 + i];
        int s = src[c0 + i];
        int b = d >> NB_SHIFT;
        int p = atomicAdd(&cur[b], 1);
        srec[p] = (unsigned)s | ((unsigned)(d & 255) << 20);
        sbkt[p] = (unsigned short)b;
    }
    __syncthreads();
    for (int i = t; i < ce; i += 512) {
        int b = sbkt[i];
        tmp[base[b] + (i - loff[b])] = srec[i];
    }
}

// one block per coarse bucket: hist -> parallel scan -> rowptr/counts/dinv,
// fine-sort into LDS staging, coalesced eidx write. (R14-measured version.)
__global__ void __launch_bounds__(512)
fill2_kernel(const int* __restrict__ gtail, const unsigned* __restrict__ tmp,
             int* __restrict__ eidx, int* __restrict__ rowptr,
             int* __restrict__ counts, float* __restrict__ dinv, int n) {
    __shared__ int hh[256];
    __shared__ int sc[256];
    __shared__ int cur[256];
    __shared__ int sout[CAP];
    int b = blockIdx.x;
    int t = threadIdx.x;
    int beg = b * CAP;
    int cnt_total = gtail[b] - beg;

    if (t < 256) hh[t] = 0;
    __syncthreads();
    for (int i = t; i < cnt_total; i += 512)
        atomicAdd(&hh[tmp[beg + i] >> 20], 1);
    __syncthreads();
    if (t < 256) sc[t] = hh[t];
    __syncthreads();
    for (int off = 1; off < 256; off <<= 1) {
        int v = 0, a = 0;
        if (t < 256) { v = sc[t]; a = (t >= off) ? sc[t - off] : 0; }
        __syncthreads();
        if (t < 256) sc[t] = v + a;
        __syncthreads();
    }
    if (t < 256) {
        int ex = sc[t] - hh[t];
        cur[t] = ex;
        int v = (b << NB_SHIFT) + t;
        if (v < n) {
            rowptr[v] = beg + ex;
            counts[v] = hh[t];
            dinv[v]   = rsqrtf((float)hh[t] + 1.0f);   // +1: self loop
        }
    }
    __syncthreads();
    for (int i = t; i < cnt_total; i += 512) {
        unsigned r = tmp[beg + i];
        int p = atomicAdd(&cur[r >> 20], 1);
        sout[p] = (int)(r & 0xFFFFF);
    }
    __syncthreads();
    for (int i = t; i < cnt_total; i += 512)
        eidx[beg + i] = sout[i];
}

// hs[row][:] = (x[row][:] @ W1) * dinv[row], stored fp16.  1 row/thread,
// 64-thread single-wave blocks; W1 via wave-uniform s_load; x prefetched
// 8-deep into registers for memory-level parallelism. (R23-measured.)
__global__ void __launch_bounds__(64)
gemm1_kernel(const float* __restrict__ x, const float* __restrict__ W1,
             const float* __restrict__ dinv, __half* __restrict__ hs, int n) {
    int row = blockIdx.x * 64 + threadIdx.x;
    if (row >= n) return;
    const float4* x4 = (const float4*)(x + (size_t)row * 256);
    const float4* W14 = (const float4*)W1;   // uniform-indexed -> s_load
    float4 a0 = {0,0,0,0}, a1 = {0,0,0,0}, a2 = {0,0,0,0}, a3 = {0,0,0,0};
    float4 buf[8];
    #pragma unroll
    for (int j = 0; j < 8; ++j) buf[j] = x4[j];
    for (int k8 = 0; k8 < 8; ++k8) {
        float4 cur[8];
        #pragma unroll
        for (int j = 0; j < 8; ++j) cur[j] = buf[j];
        if (k8 < 7) {
            #pragma unroll
            for (int j = 0; j < 8; ++j) buf[j] = x4[(k8 + 1) * 8 + j];
        }
        #pragma unroll
        for (int jj = 0; jj < 8; ++jj) {
            float4 xv = cur[jj];
            int k4 = k8 * 8 + jj;
            #pragma unroll
            for (int j = 0; j < 4; ++j) {
                float xk = (j == 0) ? xv.x : (j == 1) ? xv.y : (j == 2) ? xv.z : xv.w;
                int k = (k4 << 2) + j;
                float4 w0 = W14[k * 4 + 0];
                float4 w1 = W14[k * 4 + 1];
                float4 w2 = W14[k * 4 + 2];
                float4 w3 = W14[k * 4 + 3];
                a0.x += xk * w0.x; a0.y += xk * w0.y; a0.z += xk * w0.z; a0.w += xk * w0.w;
                a1.x += xk * w1.x; a1.y += xk * w1.y; a1.z += xk * w1.z; a1.w += xk * w1.w;
                a2.x += xk * w2.x; a2.y += xk * w2.y; a2.z += xk * w2.z; a2.w += xk * w2.w;
                a3.x += xk * w3.x; a3.y += xk * w3.y; a3.z += xk * w3.z; a3.w += xk * w3.w;
            }
        }
    }
    float di = dinv[row];
    union { __half2 h2[8]; uint4 u4[2]; } pk;
    pk.h2[0] = __floats2half2_rn(a0.x * di, a0.y * di);
    pk.h2[1] = __floats2half2_rn(a0.z * di, a0.w * di);
    pk.h2[2] = __floats2half2_rn(a1.x * di, a1.y * di);
    pk.h2[3] = __floats2half2_rn(a1.z * di, a1.w * di);
    pk.h2[4] = __floats2half2_rn(a2.x * di, a2.y * di);
    pk.h2[5] = __floats2half2_rn(a2.z * di, a2.w * di);
    pk.h2[6] = __floats2half2_rn(a3.x * di, a3.y * di);
    pk.h2[7] = __floats2half2_rn(a3.z * di, a3.w * di);
    uint4* o = (uint4*)(hs + (size_t)row * 16);
    o[0] = pk.u4[0];
    o[1] = pk.u4[1];
}

// layer-1 aggregate: 8 lanes/node = (f: 16B row-half) x (e: edge mod 4).
// Each lane gathers a FULL uint4 (8 halfs) -> 2 transactions/edge (was 4).
__global__ void agg1_kernel(const int* __restrict__ rowptr, const int* __restrict__ counts,
                            const int* __restrict__ eidx, const __half* __restrict__ hsh,
                            const float* __restrict__ dinv, const float* __restrict__ b1,
                            __half* __restrict__ gsh, int n) {
    const uint4* h4p = (const uint4*)hsh;    // 2 uint4 per 16-half row
    int t = blockIdx.x * blockDim.x + threadIdx.x;
    int v = t >> 3;
    if (v >= n) return;
    int f = t & 1, e = (t >> 1) & 3;
    int start = rowptr[v], cnt = counts[v];
    float s[8] = {0, 0, 0, 0, 0, 0, 0, 0};
    int i = e;
    for (; i + 12 < cnt; i += 16) {
        int s0 = eidx[start + i];
        int s1 = eidx[start + i + 4];
        int s2 = eidx[start + i + 8];
        int s3 = eidx[start + i + 12];
        uint4 r0 = h4p[(size_t)s0 * 2 + f];
        uint4 r1 = h4p[(size_t)s1 * 2 + f];
        uint4 r2 = h4p[(size_t)s2 * 2 + f];
        uint4 r3 = h4p[(size_t)s3 * 2 + f];
        acc8(s, r0); acc8(s, r1); acc8(s, r2); acc8(s, r3);
    }
    for (; i < cnt; i += 4) {
        uint4 r0 = h4p[(size_t)eidx[start + i] * 2 + f];
        acc8(s, r0);
    }
    // merge the four edge-groups (lane bits 1,2)
    #pragma unroll
    for (int m = 0; m < 8; ++m) {
        s[m] += __shfl_xor(s[m], 2);
        s[m] += __shfl_xor(s[m], 4);
    }
    if (e == 0) {
        float di = dinv[v];
        float h[8] = {0, 0, 0, 0, 0, 0, 0, 0};
        uint4 rv = h4p[(size_t)v * 2 + f];
        acc8(h, rv);                              // self term
        float4 ba = ((const float4*)b1)[f * 2];
        float4 bb = ((const float4*)b1)[f * 2 + 1];
        float bv[8] = {ba.x, ba.y, ba.z, ba.w, bb.x, bb.y, bb.z, bb.w};
        float z[8];
        #pragma unroll
        for (int m = 0; m < 8; ++m)
            z[m] = fmaxf(di * (s[m] + h[m]) + bv[m], 0.0f) * di;
        union { __half2 h2[4]; uint4 u4; } pk;
        #pragma unroll
        for (int m = 0; m < 4; ++m)
            pk.h2[m] = __floats2half2_rn(z[2 * m], z[2 * m + 1]);
        ((uint4*)gsh)[(size_t)v * 2 + f] = pk.u4;
    }
}

// layer-2 aggregate + factorized epilogue: u = dinv*(gather(gs)+gs);
// y = u@M + w2b; c = u.w2b.  gs fp16, same 2-transaction lane layout.
__global__ void agg2y_kernel(const int* __restrict__ rowptr, const int* __restrict__ counts,
                             const int* __restrict__ eidx, const __half* __restrict__ gsh,
                             const float* __restrict__ dinv, const float* __restrict__ mw,
                             float4* __restrict__ u4, float* __restrict__ y,
                             float* __restrict__ c, int n) {
    __shared__ float su[32 * 16];   // u for this block's 32 nodes
    __shared__ float sM[256];
    __shared__ float sw[16];
    const uint4* g4p = (const uint4*)gsh;
    int t = threadIdx.x;
    sM[t] = mw[t];
    if (t < 16) sw[t] = mw[256 + t];

    int j = t >> 3, f = t & 1, e = (t >> 1) & 3;
    int v = blockIdx.x * 32 + j;
    if (v < n) {
        int start = rowptr[v], cnt = counts[v];
        float s[8] = {0, 0, 0, 0, 0, 0, 0, 0};
        int i = e;
        for (; i + 12 < cnt; i += 16) {
            int s0 = eidx[start + i];
            int s1 = eidx[start + i + 4];
            int s2 = eidx[start + i + 8];
            int s3 = eidx[start + i + 12];
            uint4 r0 = g4p[(size_t)s0 * 2 + f];
            uint4 r1 = g4p[(size_t)s1 * 2 + f];
            uint4 r2 = g4p[(size_t)s2 * 2 + f];
            uint4 r3 = g4p[(size_t)s3 * 2 + f];
            acc8(s, r0); acc8(s, r1); acc8(s, r2); acc8(s, r3);
        }
        for (; i < cnt; i += 4) {
            uint4 r0 = g4p[(size_t)eidx[start + i] * 2 + f];
            acc8(s, r0);
        }
        #pragma unroll
        for (int m = 0; m < 8; ++m) {
            s[m] += __shfl_xor(s[m], 2);
            s[m] += __shfl_xor(s[m], 4);
        }
        if (e == 0) {
            float di = dinv[v];
            float g[8] = {0, 0, 0, 0, 0, 0, 0, 0};
            uint4 gv = g4p[(size_t)v * 2 + f];
            acc8(g, gv);                          // self term
            float uu[8];
            #pragma unroll
            for (int m = 0; m < 8; ++m) uu[m] = di * (s[m] + g[m]);
            float* up = &su[j * 16 + f * 8];
            #pragma unroll
            for (int m = 0; m < 8; ++m) up[m] = uu[m];
            float4 ua = make_float4(uu[0], uu[1], uu[2], uu[3]);
            float4 ub = make_float4(uu[4], uu[5], uu[6], uu[7]);
            u4[(size_t)v * 4 + f * 2]     = ua;
            u4[(size_t)v * 4 + f * 2 + 1] = ub;
        }
    }
    __syncthreads();
    if (v < n) {
        int l8 = t & 7;
        const float* uu = &su[j * 16];
        int c0 = l8 * 2;
        float y0 = sw[c0], y1 = sw[c0 + 1];
        #pragma unroll
        for (int k = 0; k < 16; ++k) {
            float uk = uu[k];
            y0 += uk * sM[k * 16 + c0];
            y1 += uk * sM[k * 16 + c0 + 1];
        }
        float2* yp = (float2*)(y + (size_t)v * 16 + c0);
        *yp = make_float2(y0, y1);
        if (l8 == 0) {
            float cv = 0.0f;
            #pragma unroll
            for (int k = 0; k < 16; ++k) cv += uu[k] * sw[k];
            c[v] = cv;
        }
    }
}

// 16 lanes per pair: one pos edge + one neg edge.
// logit = y[a].u[b] + c[a] + bb
__global__ void edge_dot_kernel(const int* __restrict__ pa, const int* __restrict__ pb,
                                const int* __restrict__ na, const int* __restrict__ nb_,
                                int ET, const float* __restrict__ u, const float* __restrict__ y,
                                const float* __restrict__ c, const float* __restrict__ mw,
                                float* __restrict__ out) {
    int t = blockIdx.x * blockDim.x + threadIdx.x;
    int p = t >> 4, l = t & 15;
    if (p >= ET) return;
    int a0 = pa[p], b0 = pb[p];
    int a1 = na[p], b1 = nb_[p];
    float ya0 = y[(size_t)a0 * 16 + l];
    float ub0 = u[(size_t)b0 * 16 + l];
    float ya1 = y[(size_t)a1 * 16 + l];
    float ub1 = u[(size_t)b1 * 16 + l];
    float p0 = ya0 * ub0;
    float p1 = ya1 * ub1;
    p0 += __shfl_xor(p0, 1);  p1 += __shfl_xor(p1, 1);
    p0 += __shfl_xor(p0, 2);  p1 += __shfl_xor(p1, 2);
    p0 += __shfl_xor(p0, 4);  p1 += __shfl_xor(p1, 4);
    p0 += __shfl_xor(p0, 8);  p1 += __shfl_xor(p1, 8);
    if (l == 0) {
        float bb = mw[272];
        out[p]      = p0 + c[a0] + bb;
        out[ET + p] = p1 + c[a1] + bb;
    }
}

extern "C" void kernel_launch(void* const* d_in, const int* in_sizes, int n_in,
                              void* d_out, int out_size, void* d_ws, size_t ws_size,
                              hipStream_t stream) {
    const float* x    = (const float*)d_in[0];
    const int*   tei  = (const int*)d_in[1];
    const int*   tpos = (const int*)d_in[2];
    const int*   tneg = (const int*)d_in[3];
    const float* W1   = (const float*)d_in[4];
    const float* b1   = (const float*)d_in[5];
    const float* W2   = (const float*)d_in[6];
    const float* b2   = (const float*)d_in[7];
    float* out = (float*)d_out;

    int n   = in_sizes[0] / 256;         // 100000 nodes
    int E   = in_sizes[1] / 2;           // 3.2M train edges
    int ET  = in_sizes[2] / 2;           // 500K test edges each
    int nb1 = (n + 255) >> NB_SHIFT;     // 391 coarse buckets (256 nodes each)

    // workspace layout (no aliasing)
    char* w = (char*)d_ws;
    int*   gtail  = (int*)w;        w += 512 * 4;
    float* mw     = (float*)w;      w += 512 * 4;
    int*   rowptr = (int*)w;        w += (size_t)n * 4;
    int*   counts = (int*)w;        w += (size_t)n * 4;
    float* dinv   = (float*)w;      w += (size_t)n * 4;
    __half* hs    = (__half*)w;     w += (size_t)16 * n * 2;   // fp16 table
    __half* gs    = (__half*)w;     w += (size_t)16 * n * 2;   // fp16 table
    float* u      = (float*)w;      w += (size_t)16 * n * 4;
    float* y      = (float*)w;      w += (size_t)16 * n * 4;
    float* c      = (float*)w;      w += (size_t)n * 4;
    int*   eidx   = (int*)w;        w += (size_t)nb1 * CAP * 4;
    unsigned* tmp = (unsigned*)w;   w += (size_t)nb1 * CAP * 4;

    const int* src = tei;
    const int* dst = tei + E;

    seedprep_kernel<<<1, 256, 0, stream>>>(gtail, nb1, W2, b2, mw);
    passA1_kernel<<<(E + CHUNK - 1) / CHUNK, 512, 0, stream>>>(src, dst, E, gtail, tmp, nb1);
    fill2_kernel<<<nb1, 512, 0, stream>>>(gtail, tmp, eidx, rowptr, counts, dinv, n);

    gemm1_kernel<<<(n + 63) / 64, 64, 0, stream>>>(x, W1, dinv, hs, n);
    agg1_kernel<<<(8 * n + 255) / 256, 256, 0, stream>>>(rowptr, counts, eidx,
                                                         hs, dinv, b1, gs, n);
    agg2y_kernel<<<(n + 31) / 32, 256, 0, stream>>>(rowptr, counts, eidx,
                                                    gs, dinv, mw,
                                                    (float4*)u, y, c, n);
    edge_dot_kernel<<<(16 * ET + 255) / 256, 256, 0, stream>>>(tpos, tpos + ET, tneg, tneg + ET,
                                                               ET, u, y, c, mw, out);
}